// Round 5
// baseline (1773.232 us; speedup 1.0000x reference)
//
#include <hip/hip_runtime.h>
#include <cstdint>
#include <cstddef>

// Problem constants
#define BB 16
#define NN 1024
#define HD 256
#define IND 128
#define OUTD 1024
#define MROWS (BB*NN)          // 16384
#define NBLK 256               // persistent sinkhorn grid (= CU count)

#define LEAKY(x) ((x) >= 0.0f ? (x) : 0.01f*(x))

typedef short short8 __attribute__((ext_vector_type(8)));
typedef float f32x4 __attribute__((ext_vector_type(4)));

// 16B async global->LDS DMA. LDS dest linear; swizzle on global source + read.
#define GLL16(gsrc, ldst) __builtin_amdgcn_global_load_lds( \
    (const __attribute__((address_space(1))) unsigned int*)(gsrc), \
    (__attribute__((address_space(3))) unsigned int*)(ldst), 16, 0, 0)

// compiler-level memory fence — stops LDS ops crossing raw s_barrier
#define CFENCE() asm volatile("" ::: "memory")

// ---------------- wave helpers ----------------
__device__ inline float wave_sum(float v){
  #pragma unroll
  for (int off=32; off; off>>=1) v += __shfl_xor(v, off, 64);
  return v;
}
__device__ inline float wave_max(float v){
  #pragma unroll
  for (int off=32; off; off>>=1) v = fmaxf(v, __shfl_xor(v, off, 64));
  return v;
}

// fp32 -> bf16 round-to-nearest-even; bf16 -> fp32
__device__ inline unsigned short f2bf(float x){
  unsigned u = __float_as_uint(x);
  unsigned r = (u + 0x7fffu + ((u >> 16) & 1u)) >> 16;
  return (unsigned short)r;
}
__device__ inline float bf2f(unsigned short h){
  return __uint_as_float((unsigned)h << 16);
}

// ---- custom 8-bit float for E in (0,1]: k=(E<<3)|M, E=e-96 (e=f32 biased exp)
// value = (1+M/8)*2^(E-31); k=248 -> 1.0; floor 2^-30 (below -> 0). rel err <=6%.
__device__ inline unsigned enc_e(float x){
  unsigned u = __float_as_uint(x);
  u += 0x7FFFFu + ((u>>20)&1u);          // RTNE at 3 mantissa bits
  unsigned e = u>>23;
  if (e < 97u) return 0u;
  return ((e-96u)<<3) | ((u>>20)&7u);
}
__device__ inline float dec_e(unsigned k){
  float nrm = __uint_as_float((k + 768u) << 20);
  return k ? nrm : 0.0f;
}

// ---------------- device-scope grid barrier (co-resident grid only) ----------------
__device__ inline void gsync(unsigned* bar){
  asm volatile("s_waitcnt vmcnt(0)" ::: "memory");   // drain this wave's stores
  __syncthreads();
  if (threadIdx.x == 0){
    unsigned g = __hip_atomic_load(&bar[1], __ATOMIC_RELAXED, __HIP_MEMORY_SCOPE_AGENT);
    unsigned o = __hip_atomic_fetch_add(&bar[0], 1u, __ATOMIC_RELAXED, __HIP_MEMORY_SCOPE_AGENT);
    if (o == NBLK-1u){
      __hip_atomic_store(&bar[0], 0u, __ATOMIC_RELAXED, __HIP_MEMORY_SCOPE_AGENT);
      __hip_atomic_fetch_add(&bar[1], 1u, __ATOMIC_RELEASE, __HIP_MEMORY_SCOPE_AGENT);
    } else {
      while (__hip_atomic_load(&bar[1], __ATOMIC_RELAXED, __HIP_MEMORY_SCOPE_AGENT) == g)
        __builtin_amdgcn_s_sleep(16);
    }
  }
  __syncthreads();
}

// ---------------- JAX threefry2x32 gumbel noise (partitionable) ----------------
__device__ inline float gumbel_noise(unsigned m){
  const unsigned k0 = 0u, k1 = 42u;
  const unsigned ks2 = k0 ^ k1 ^ 0x1BD11BDAu;
  unsigned x0 = 0u, x1 = m;
  x0 += k0; x1 += k1;
  #define TF_ROUND(r) { x0 += x1; x1 = (x1 << (r)) | (x1 >> (32-(r))); x1 ^= x0; }
  TF_ROUND(13) TF_ROUND(15) TF_ROUND(26) TF_ROUND(6)
  x0 += k1;  x1 += ks2 + 1u;
  TF_ROUND(17) TF_ROUND(29) TF_ROUND(16) TF_ROUND(24)
  x0 += ks2; x1 += k0 + 2u;
  TF_ROUND(13) TF_ROUND(15) TF_ROUND(26) TF_ROUND(6)
  x0 += k0;  x1 += k1 + 3u;
  TF_ROUND(17) TF_ROUND(29) TF_ROUND(16) TF_ROUND(24)
  x0 += k1;  x1 += ks2 + 4u;
  TF_ROUND(13) TF_ROUND(15) TF_ROUND(26) TF_ROUND(6)
  x0 += ks2; x1 += k0 + 5u;
  #undef TF_ROUND
  unsigned bits = x0 ^ x1;
  float u = __uint_as_float((bits >> 9) | 0x3f800000u) - 1.0f;   // [0,1)
  float t = -__logf(u + 1e-20f);
  return -__logf(t + 1e-20f) * 0.05f;   // NOISE_SCALE
}

// ---------------- fused adj row stats + bf16 convert ----------------
__global__ __launch_bounds__(256) void adj_prep_k(const float* __restrict__ adj,
                                                  float* __restrict__ dis,
                                                  float* __restrict__ rinv,
                                                  unsigned short* __restrict__ abf){
  int tid = threadIdx.x, wid = tid >> 6, lane = tid & 63;
  int row = blockIdx.x*4 + wid;
  const float4* rp = (const float4*)(adj + (size_t)row*NN);
  ushort4* op = (ushort4*)(abf + (size_t)row*NN);
  float s = 0.f;
  #pragma unroll
  for (int p=0;p<4;p++){
    float4 v = rp[lane + p*64];
    s += v.x+v.y+v.z+v.w;
    ushort4 o;
    o.x = f2bf(v.x); o.y = f2bf(v.y); o.z = f2bf(v.z); o.w = f2bf(v.w);
    op[lane + p*64] = o;
  }
  s = wave_sum(s);
  if (lane==0){
    dis[row]  = 1.0f/sqrtf(s + 1.0f);
    rinv[row] = 1.0f/s;
  }
}

// ---------------- flat hi/lo split ----------------
__global__ __launch_bounds__(256) void split_flat_k(const float* __restrict__ src,
                                                    unsigned short* __restrict__ h,
                                                    unsigned short* __restrict__ l,
                                                    int n4){
  int gid = blockIdx.x*256 + threadIdx.x;
  if (gid >= n4) return;
  float4 v = ((const float4*)src)[gid];
  ushort4 hh, ll;
  hh.x = f2bf(v.x); ll.x = f2bf(v.x - bf2f(hh.x));
  hh.y = f2bf(v.y); ll.y = f2bf(v.y - bf2f(hh.y));
  hh.z = f2bf(v.z); ll.z = f2bf(v.z - bf2f(hh.z));
  hh.w = f2bf(v.w); ll.w = f2bf(v.w - bf2f(hh.w));
  ((ushort4*)h)[gid] = hh;
  ((ushort4*)l)[gid] = ll;
}

// fp32 [16][1024 i][ld] (cols 0..255) -> bf16 transposed [16][256 c][1024 i]
__global__ __launch_bounds__(256) void bconv_t_k(const float* __restrict__ in, int ld,
                                                 const float* __restrict__ scale,
                                                 unsigned short* __restrict__ outT){
  __shared__ float tile[64][68];
  int b  = blockIdx.z;
  int i0 = blockIdx.x*64;
  int c0 = blockIdx.y*64;
  const float* inb = in + (size_t)b*NN*ld;
  unsigned short* ob = outT + (size_t)b*HD*NN;
  int tid = threadIdx.x;
  #pragma unroll
  for (int it=0; it<4; it++){
    int f = tid + it*256;
    int r = f >> 4, c4 = (f & 15)*4;
    float4 v = *(const float4*)(inb + (size_t)(i0+r)*ld + c0 + c4);
    float s = scale ? scale[b*NN + i0 + r] : 1.0f;
    tile[r][c4+0]=v.x*s; tile[r][c4+1]=v.y*s; tile[r][c4+2]=v.z*s; tile[r][c4+3]=v.w*s;
  }
  __syncthreads();
  #pragma unroll
  for (int it=0; it<4; it++){
    int f = tid + it*256;
    int cl = f >> 4, r4 = (f & 15)*4;
    ushort4 o;
    o.x = f2bf(tile[r4+0][cl]);
    o.y = f2bf(tile[r4+1][cl]);
    o.z = f2bf(tile[r4+2][cl]);
    o.w = f2bf(tile[r4+3][cl]);
    *(ushort4*)(ob + (size_t)(c0+cl)*NN + i0 + r4) = o;
  }
}

// ---------------- MFMA batched GEMM: acc = adj[b] @ B[b] ----------------
// ring-4, stage-ahead-2, counted vmcnt(4), ONE barrier per K-step, XCD swizzle.
// mode 1: o = 0.5*(Bsrc[i][n] + sc_i*acc)
// mode 2: o = leaky(sc_i*(acc + sc_i*Bsrc[i][n]))
__global__ __launch_bounds__(512) void gemm_nn_mfma_k(const unsigned short* __restrict__ Abf,
                                                      const unsigned short* __restrict__ Btb,
                                                      const float* __restrict__ Bsrc, int ldb,
                                                      const float* __restrict__ rowscale,
                                                      float* __restrict__ out,
                                                      float* __restrict__ out2,
                                                      const float* __restrict__ sub,
                                                      int mode){
  __shared__ unsigned short Als[4][128][32];   // 32 KB
  __shared__ unsigned short Bls[4][128][32];   // 32 KB
  // XCD swizzle: nwg=256; consecutive s round-robin XCDs -> chunk per XCD
  int s = blockIdx.x + (blockIdx.y<<1) + (blockIdx.z<<4);
  int idx = (s&7)*32 + (s>>3);
  int b  = idx >> 4;
  int i0 = ((idx>>1)&7)*128;
  int n0 = (idx&1)*128;
  const unsigned short* Ab = Abf + (size_t)b*NN*NN + (size_t)i0*NN;
  const unsigned short* Bb = Btb + (size_t)b*HD*NN + (size_t)n0*NN;
  int tid = threadIdx.x;
  int wave = tid >> 6, lane = tid & 63;
  int quad = lane >> 4, l16 = lane & 15;
  int wr = (wave >> 2)*64;
  int wc = (wave & 3)*32;

  int r  = tid >> 2;
  int cg = (((tid & 3) ^ ((r >> 1) & 3)) << 3);   // swizzled source col
  int wbase = (tid >> 6) << 9;                    // wave's 1KB chunk in a tile
  const unsigned short* gA = Ab + (size_t)r*NN + cg;
  const unsigned short* gB = Bb + (size_t)r*NN + cg;

  auto STAGE = [&](int t){
    int buf = t & 3;
    GLL16(gA + (t<<5), &Als[buf][0][0] + wbase);
    GLL16(gB + (t<<5), &Bls[buf][0][0] + wbase);
  };

  const int NT = NN/32;   // 32
  STAGE(0); STAGE(1);

  f32x4 acc[4][2] = {};

  for (int t = 0; t < NT; ++t){
    if (t+2 < NT){
      STAGE(t+2);
      asm volatile("s_waitcnt vmcnt(4)" ::: "memory");
    } else if (t+1 < NT){
      asm volatile("s_waitcnt vmcnt(2)" ::: "memory");
    } else {
      asm volatile("s_waitcnt vmcnt(0)" ::: "memory");
    }
    __builtin_amdgcn_s_barrier();
    CFENCE();
    int buf = t & 3;
    short8 af[4];
    #pragma unroll
    for (int rt=0; rt<4; rt++){
      int R = wr + rt*16 + l16;
      af[rt] = *(const short8*)&Als[buf][R][(quad ^ ((R >> 1) & 3)) << 3];
    }
    __builtin_amdgcn_s_setprio(1);
    #pragma unroll
    for (int ct=0; ct<2; ct++){
      int Rb = wc + ct*16 + l16;
      short8 bfr = *(const short8*)&Bls[buf][Rb][(quad ^ ((Rb >> 1) & 3)) << 3];
      #pragma unroll
      for (int rt=0; rt<4; rt++)
        acc[rt][ct] = __builtin_amdgcn_mfma_f32_16x16x32_bf16(af[rt], bfr, acc[rt][ct], 0, 0, 0);
    }
    __builtin_amdgcn_s_setprio(0);
  }

  #pragma unroll
  for (int rt=0; rt<4; rt++){
    #pragma unroll
    for (int p=0; p<4; p++){
      int gr = i0 + wr + rt*16 + quad*4 + p;
      int gm = b*NN + gr;
      float sc = rowscale[gm];
      #pragma unroll
      for (int ct=0; ct<2; ct++){
        int gc = n0 + wc + ct*16 + l16;
        float a = acc[rt][ct][p];
        float src = Bsrc[(size_t)gm*ldb + gc];
        float o = (mode == 1) ? 0.5f*(src + sc*a) : LEAKY(sc*(a + sc*src));
        if (out) out[(size_t)gm*HD + gc] = o;
        if (out2){
          float sv = sub ? sub[(size_t)gm*HD + gc] : src;
          out2[(size_t)gm*HD + gc] = fabsf(sv - o);
        }
      }
    }
  }
}

// ---------------- split-bf16 MFMA linear: out = act(A @ W^T + bias) ----------------
// Interleaved 4-tile K-chunks (each tile read ONCE), ring-2 slots, stage-ahead-1,
// counted vmcnt(4), 2 barriers/step, XCD swizzle.
// act 0: none, 1: leaky, 2: sinkhorn init (Z0 = (40*tanh(x)+gumbel)/0.1)
__global__ __launch_bounds__(512) void gemm_nt_mfma_k(const unsigned short* __restrict__ Ah_,
                                                      const unsigned short* __restrict__ Al_,
                                                      int lda,
                                                      const unsigned short* __restrict__ Wh_,
                                                      const unsigned short* __restrict__ Wl_,
                                                      const float* __restrict__ bias,
                                                      float* __restrict__ out, int ldo,
                                                      unsigned short* __restrict__ outh,
                                                      unsigned short* __restrict__ outl,
                                                      int K, int act){
  __shared__ unsigned short AhL[2][128][32], AlL[2][128][32];   // 32 KB
  __shared__ unsigned short WhL[2][128][32], WlL[2][128][32];   // 32 KB
  int gx = gridDim.x;
  int sh = (gx == 2) ? 1 : 3;                 // log2(gx); gx in {2,8}
  int s = blockIdx.x + blockIdx.y*gx;
  int nwg = gx*gridDim.y;
  int idx = (s&7)*(nwg>>3) + (s>>3);
  int o0 = (idx & (gx-1))*128;
  int m0 = (idx >> sh)*128;
  int tid = threadIdx.x;
  int wave = tid >> 6, lane = tid & 63;
  int quad = lane >> 4, l16 = lane & 15;
  int wr = (wave >> 2)*64;
  int wc = (wave & 3)*32;

  int r  = tid >> 2;
  int cg = (((tid & 3) ^ ((r >> 1) & 3)) << 3);
  int wbase = (tid >> 6) << 9;
  const unsigned short* gAh = Ah_ + (size_t)(m0 + r)*lda + cg;
  const unsigned short* gAl = Al_ + (size_t)(m0 + r)*lda + cg;
  const unsigned short* gWh = Wh_ + (size_t)(o0 + r)*K + cg;
  const unsigned short* gWl = Wl_ + (size_t)(o0 + r)*K + cg;

  int NC = K >> 5;

  auto STAGE = [&](int c){
    int buf = c & 1; int kc = c << 5;
    GLL16(gAh + kc, &AhL[buf][0][0] + wbase);
    GLL16(gAl + kc, &AlL[buf][0][0] + wbase);
    GLL16(gWh + kc, &WhL[buf][0][0] + wbase);
    GLL16(gWl + kc, &WlL[buf][0][0] + wbase);
  };

  STAGE(0);

  f32x4 acc[4][2] = {};

  for (int c = 0; c < NC; ++c){
    if (c+1 < NC){
      STAGE(c+1);
      asm volatile("s_waitcnt vmcnt(4)" ::: "memory");
    } else {
      asm volatile("s_waitcnt vmcnt(0)" ::: "memory");
    }
    __builtin_amdgcn_s_barrier();
    CFENCE();
    int buf = c & 1;
    short8 ah[4], al[4];
    #pragma unroll
    for (int rt=0; rt<4; rt++){
      int R = wr + rt*16 + l16;
      int sc = (quad ^ ((R >> 1) & 3)) << 3;
      ah[rt] = *(const short8*)&AhL[buf][R][sc];
      al[rt] = *(const short8*)&AlL[buf][R][sc];
    }
    __builtin_amdgcn_s_setprio(1);
    #pragma unroll
    for (int ct=0; ct<2; ct++){
      int Rb = wc + ct*16 + l16;
      int sc = (quad ^ ((Rb >> 1) & 3)) << 3;
      short8 wh = *(const short8*)&WhL[buf][Rb][sc];
      short8 wl = *(const short8*)&WlL[buf][Rb][sc];
      #pragma unroll
      for (int rt=0; rt<4; rt++){
        acc[rt][ct] = __builtin_amdgcn_mfma_f32_16x16x32_bf16(ah[rt], wh, acc[rt][ct], 0, 0, 0);
        acc[rt][ct] = __builtin_amdgcn_mfma_f32_16x16x32_bf16(al[rt], wh, acc[rt][ct], 0, 0, 0);
        acc[rt][ct] = __builtin_amdgcn_mfma_f32_16x16x32_bf16(ah[rt], wl, acc[rt][ct], 0, 0, 0);
      }
    }
    __builtin_amdgcn_s_setprio(0);
    CFENCE();
    __builtin_amdgcn_s_barrier();
    CFENCE();
  }

  #pragma unroll
  for (int rt=0; rt<4; rt++){
    #pragma unroll
    for (int p=0; p<4; p++){
      int gm = m0 + wr + rt*16 + quad*4 + p;
      #pragma unroll
      for (int ct=0; ct<2; ct++){
        int gc = o0 + wc + ct*16 + l16;
        float v = acc[rt][ct][p] + bias[gc];
        if (act == 1){
          v = LEAKY(v);
        } else if (act == 2){
          float vcl = fminf(fmaxf(v, -15.f), 15.f);
          float e = __expf(2.f*vcl);
          float lg = 40.0f * (e - 1.f) / (e + 1.f);
          unsigned flat = (unsigned)gm*1024u + (unsigned)gc;
          v = (lg + gumbel_noise(flat)) / 0.1f;
        }
        if (out) out[(size_t)gm*ldo + gc] = v;
        if (outh){
          unsigned short hh = f2bf(v);
          outh[(size_t)gm*ldo + gc] = hh;
          outl[(size_t)gm*ldo + gc] = f2bf(v - bf2f(hh));
        }
      }
    }
  }
}

// ---------------- channel attention + combine (writes split bf16 hi/lo) ----------------
__global__ __launch_bounds__(256) void attn_k(const float* __restrict__ c0,
                                              const float* __restrict__ s0,
                                              const float* __restrict__ s1,
                                              const float* __restrict__ s2,
                                              const float* __restrict__ a2,
                                              unsigned short* __restrict__ outh,
                                              unsigned short* __restrict__ outl){
  int tid = threadIdx.x, wid = tid >> 6, lane = tid & 63;
  int row = blockIdx.x*4 + wid;
  size_t base = (size_t)row*HD + lane*4;
  float4 av = *(const float4*)(a2 + lane*4);
  float4 v[4];
  v[0] = *(const float4*)(c0 + base);
  v[1] = *(const float4*)(s0 + base);
  v[2] = *(const float4*)(s1 + base);
  v[3] = *(const float4*)(s2 + base);
  float e[4];
  #pragma unroll
  for (int c=0;c<4;c++){
    float p = fmaxf(v[c].x,0.f)*av.x + fmaxf(v[c].y,0.f)*av.y
            + fmaxf(v[c].z,0.f)*av.z + fmaxf(v[c].w,0.f)*av.w;
    e[c] = wave_sum(p);
  }
  float m = fmaxf(fmaxf(e[0],e[1]), fmaxf(e[2],e[3]));
  float w0 = expf(e[0]-m), w1 = expf(e[1]-m), w2 = expf(e[2]-m), w3 = expf(e[3]-m);
  float inv = 0.25f / (w0+w1+w2+w3);
  float4 o;
  o.x = (w0*v[0].x + w1*v[1].x + w2*v[2].x + w3*v[3].x)*inv;
  o.y = (w0*v[0].y + w1*v[1].y + w2*v[2].y + w3*v[3].y)*inv;
  o.z = (w0*v[0].z + w1*v[1].z + w2*v[2].z + w3*v[3].z)*inv;
  o.w = (w0*v[0].w + w1*v[1].w + w2*v[2].w + w3*v[3].w)*inv;
  ushort4 oh, ol;
  oh.x = f2bf(o.x); ol.x = f2bf(o.x - bf2f(oh.x));
  oh.y = f2bf(o.y); ol.y = f2bf(o.y - bf2f(oh.y));
  oh.z = f2bf(o.z); ol.z = f2bf(o.z - bf2f(oh.z));
  oh.w = f2bf(o.w); ol.w = f2bf(o.w - bf2f(oh.w));
  *(ushort4*)(outh + base) = oh;
  *(ushort4*)(outl + base) = ol;
}

// ================= linear-domain Sinkhorn (8-bit E) =================
// fused rowmax + partial colmax: one HBM pass over Z0
__global__ __launch_bounds__(256) void rowcolmax_k(const float* __restrict__ Z,
                                                   float* __restrict__ alpha,
                                                   float* __restrict__ pmax){
  __shared__ float al[64];
  int tid = threadIdx.x, wid = tid >> 6, lane = tid & 63;
  int blk = blockIdx.x;             // 256 blocks, 64-row stripes
  int r0 = blk << 6;
  #pragma unroll 1
  for (int rr=0; rr<16; ++rr){
    int lr = (wid<<4) + rr;
    const float4* rp = (const float4*)(Z + ((size_t)(r0+lr)<<10));
    float m = -3.4e38f;
    #pragma unroll
    for (int p4=0;p4<4;p4++){
      float4 v = rp[lane + p4*64];
      m = fmaxf(m, fmaxf(fmaxf(v.x,v.y), fmaxf(v.z,v.w)));
    }
    m = wave_max(m);
    if (lane==0){ al[lr] = m; alpha[r0+lr] = m; }
  }
  __syncthreads();
  int j = tid*4;
  float4 mm = make_float4(-3.4e38f,-3.4e38f,-3.4e38f,-3.4e38f);
  #pragma unroll 4
  for (int rr=0; rr<64; ++rr){
    float4 v = *(const float4*)(Z + ((size_t)(r0+rr)<<10) + j);
    float a = al[rr];
    mm.x = fmaxf(mm.x, v.x-a); mm.y = fmaxf(mm.y, v.y-a);
    mm.z = fmaxf(mm.z, v.z-a); mm.w = fmaxf(mm.w, v.w-a);
  }
  *(float4*)(pmax + ((size_t)blk<<10) + j) = mm;
}

__global__ __launch_bounds__(256) void colred_k(const float* __restrict__ pmax,
                                                float* __restrict__ beta){
  int b = blockIdx.y;
  int j = blockIdx.x*256 + threadIdx.x;
  float m = -3.4e38f;
  #pragma unroll
  for (int rc=0; rc<16; rc++)
    m = fmaxf(m, pmax[((size_t)(b*16+rc)<<10) + j]);
  beta[b*NN + j] = m;
}

// build E (8-bit row-major) and E^T (8-bit)
__global__ __launch_bounds__(256) void build_e_k(const float* __restrict__ Z,
                                                 const float* __restrict__ alpha,
                                                 const float* __restrict__ beta,
                                                 unsigned char* __restrict__ E,
                                                 unsigned char* __restrict__ Et){
  __shared__ float tile[64][65];
  int b = blockIdx.z;
  int i0 = blockIdx.y*64, j0 = blockIdx.x*64;
  const float* Zb = Z + (size_t)b*NN*NN;
  const float* ab = alpha + b*NN;
  const float* bb = beta  + b*NN;
  unsigned char* Eb  = E  + (size_t)b*NN*NN;
  unsigned char* Etb = Et + (size_t)b*NN*NN;
  int tid = threadIdx.x;
  #pragma unroll
  for (int it=0; it<4; it++){
    int f = tid + it*256;
    int r = f >> 4, c4 = (f & 15)*4;
    float4 v = *(const float4*)(Zb + (size_t)(i0+r)*NN + j0 + c4);
    float a = ab[i0+r];
    float e0 = __expf(v.x - a - bb[j0+c4+0]);
    float e1 = __expf(v.y - a - bb[j0+c4+1]);
    float e2 = __expf(v.z - a - bb[j0+c4+2]);
    float e3 = __expf(v.w - a - bb[j0+c4+3]);
    tile[r][c4+0]=e0; tile[r][c4+1]=e1; tile[r][c4+2]=e2; tile[r][c4+3]=e3;
    uchar4 o;
    o.x=(unsigned char)enc_e(e0); o.y=(unsigned char)enc_e(e1);
    o.z=(unsigned char)enc_e(e2); o.w=(unsigned char)enc_e(e3);
    *(uchar4*)(Eb + (size_t)(i0+r)*NN + j0 + c4) = o;
  }
  __syncthreads();
  #pragma unroll
  for (int it=0; it<4; it++){
    int f = tid + it*256;
    int r = f >> 4, c4 = (f & 15)*4;
    uchar4 o;
    o.x = (unsigned char)enc_e(tile[c4+0][r]);
    o.y = (unsigned char)enc_e(tile[c4+1][r]);
    o.z = (unsigned char)enc_e(tile[c4+2][r]);
    o.w = (unsigned char)enc_e(tile[c4+3][r]);
    *(uchar4*)(Etb + (size_t)(j0+r)*NN + i0 + c4) = o;
  }
}

// persistent Sinkhorn: 42 mv phases + P write, one kernel, grid barrier.
// phases: p even -> a = 1/(E b) (p0: b=1); p odd -> b = 1/(Et a); p41 -> t = Et a (no recip)
__global__ __launch_bounds__(256, 1) void sinkhorn_pers_k(const unsigned char* __restrict__ E,
                                                          const unsigned char* __restrict__ Et,
                                                          float* __restrict__ av,
                                                          float* __restrict__ bv,
                                                          float* __restrict__ tv,
                                                          unsigned* __restrict__ bar,
                                                          float* __restrict__ P){
  int tid = threadIdx.x, wid = tid >> 6, lane = tid & 63;
  int blk = blockIdx.x;
  int r0 = blk << 6;                 // 64 rows per block
  int vbase = (r0 >> 10) << 10;      // batch base for vectors

  float vreg[16];
  #pragma unroll
  for (int q=0;q<16;q++) vreg[q] = 1.0f;

  #define DECSUM(mwp, base) ( \
      dec_e( (mwp)      &255u)*vreg[base+0] + dec_e(((mwp)>>8 )&255u)*vreg[base+1] + \
      dec_e(((mwp)>>16) &255u)*vreg[base+2] + dec_e( (mwp)>>24       )*vreg[base+3] )

  for (int p = 0; p < 42; ++p){
    const unsigned char* M = (p & 1) ? Et : E;
    float* wout = (p & 1) ? ((p == 41) ? tv : bv) : av;
    int recip = (p != 41);
    #pragma unroll 1
    for (int rr=0; rr<16; ++rr){
      int row = r0 + (wid<<4) + rr;
      uint4 mw = *((const uint4*)(M + ((size_t)row<<10)) + lane);
      float s = DECSUM(mw.x,0) + DECSUM(mw.y,4) + DECSUM(mw.z,8) + DECSUM(mw.w,12);
      s = wave_sum(s);
      if (lane==0){
        float o = recip ? 1.0f/s : s;
        __hip_atomic_store(&wout[row], o, __ATOMIC_RELAXED, __HIP_MEMORY_SCOPE_AGENT);
      }
    }
    gsync(bar);
    if (p < 41){
      const float* vin = (p & 1) ? bv : av;   // next phase's input
      #pragma unroll
      for (int q=0;q<16;q++)
        vreg[q] = __hip_atomic_load(&vin[vbase + lane*16 + q],
                                    __ATOMIC_RELAXED, __HIP_MEMORY_SCOPE_AGENT);
    }
  }
  #undef DECSUM

  // P = E * a' / t'
  float tinv[16];
  #pragma unroll
  for (int q=0;q<16;q++){
    float t = __hip_atomic_load(&tv[vbase + lane*16 + q],
                                __ATOMIC_RELAXED, __HIP_MEMORY_SCOPE_AGENT);
    tinv[q] = 1.0f/t;
  }
  #pragma unroll 1
  for (int rr=0; rr<16; ++rr){
    int row = r0 + (wid<<4) + rr;
    float a = __hip_atomic_load(&av[row], __ATOMIC_RELAXED, __HIP_MEMORY_SCOPE_AGENT);
    uint4 mw = *((const uint4*)(E + ((size_t)row<<10)) + lane);
    float* Pr = P + ((size_t)row<<10) + lane*16;
    float4 o;
    o.x = dec_e( mw.x      &255u)*a*tinv[0];
    o.y = dec_e((mw.x>>8 ) &255u)*a*tinv[1];
    o.z = dec_e((mw.x>>16) &255u)*a*tinv[2];
    o.w = dec_e( mw.x>>24        )*a*tinv[3];
    *(float4*)(Pr+0) = o;
    o.x = dec_e( mw.y      &255u)*a*tinv[4];
    o.y = dec_e((mw.y>>8 ) &255u)*a*tinv[5];
    o.z = dec_e((mw.y>>16) &255u)*a*tinv[6];
    o.w = dec_e( mw.y>>24        )*a*tinv[7];
    *(float4*)(Pr+4) = o;
    o.x = dec_e( mw.z      &255u)*a*tinv[8];
    o.y = dec_e((mw.z>>8 ) &255u)*a*tinv[9];
    o.z = dec_e((mw.z>>16) &255u)*a*tinv[10];
    o.w = dec_e( mw.z>>24        )*a*tinv[11];
    *(float4*)(Pr+8) = o;
    o.x = dec_e( mw.w      &255u)*a*tinv[12];
    o.y = dec_e((mw.w>>8 ) &255u)*a*tinv[13];
    o.z = dec_e((mw.w>>16) &255u)*a*tinv[14];
    o.w = dec_e( mw.w>>24        )*a*tinv[15];
    *(float4*)(Pr+12) = o;
  }
}

// ---------------- host orchestration ----------------
extern "C" void kernel_launch(void* const* d_in, const int* in_sizes, int n_in,
                              void* d_out, int out_size, void* d_ws, size_t ws_size,
                              hipStream_t stream){
  const float* X    = (const float*)d_in[0];
  const float* adj  = (const float*)d_in[1];
  const float* w_in = (const float*)d_in[2];
  const float* b_in = (const float*)d_in[3];
  const float* cw1  = (const float*)d_in[4];
  const float* cb1  = (const float*)d_in[5];
  const float* cw2  = (const float*)d_in[6];
  const float* cb2  = (const float*)d_in[7];
  const float* ca   = (const float*)d_in[8];
  const float* m1w  = (const float*)d_in[9];
  const float* m1b  = (const float*)d_in[10];
  const float* m2w  = (const float*)d_in[11];
  const float* m2b  = (const float*)d_in[12];

  float* outp = (float*)d_out;
  float* Pout = outp;                              // [0,16M) floats
  float* Z0   = outp + (size_t)16*1024*1024;       // bytes [64,128)MB

  const size_t SLOT = (size_t)4*1024*1024;
  float* s1 = outp + 0*SLOT;
  float* s2 = outp + 1*SLOT;
  float* s3 = outp + 2*SLOT;
  float* s4 = outp + 3*SLOT;
  float* s5 = outp + 4*SLOT;
  unsigned short* adjbf = (unsigned short*)(outp + 6*SLOT);   // [96,128) MB

  unsigned short* Xh  = (unsigned short*)(outp + 0*SLOT);
  unsigned short* Xl  = Xh + (size_t)MROWS*IND;
  unsigned short* s4h = (unsigned short*)(outp + 3*SLOT);
  unsigned short* s4l = s4h + (size_t)MROWS*HD;
  unsigned short* l1h = (unsigned short*)(outp + 0*SLOT);
  unsigned short* l1l = l1h + (size_t)MROWS*HD;
  unsigned short* m1sh = (unsigned short*)(outp + 1*SLOT);
  unsigned short* m1sl = m1sh + (size_t)MROWS*HD;
  unsigned short* Hh = (unsigned short*)(outp + 2*SLOT);      // 24 MB
  unsigned short* Hl = Hh + (size_t)MROWS*768;                // 24 MB
  // sinkhorn stabilizers in slot 0 (dead before P write)
  float* alpha = s1;                 // 64 KB
  float* beta  = s1 + 16384;         // 64 KB
  float* pmaxb = s1 + 32768;         // 1 MB (256*1024)

  float* ws     = (float*)d_ws;
  float* hidden = ws;                                   // 12M floats (layers)
  float* dis    = ws + (size_t)12*1024*1024;
  float* rinv   = dis + 16384;
  unsigned short* bt = (unsigned short*)(rinv + 16384); // 8 MiB
  unsigned short* wsp = (unsigned short*)(ws + (size_t)15*1024*1024);
  unsigned short* winh = wsp;               unsigned short* winl = winh + 32768;
  unsigned short* w1h  = winl + 32768;      unsigned short* w1l  = w1h + 131072;
  unsigned short* w2h  = w1l + 131072;      unsigned short* w2l  = w2h + 131072;
  unsigned short* m1h  = w2l + 131072;      unsigned short* m1l  = m1h + 196608;
  unsigned short* m2h  = m1l + 196608;      unsigned short* m2l  = m2h + 262144;
  unsigned char* E  = (unsigned char*)ws;               // 16 MiB (post-layers)
  unsigned char* Et = E + (size_t)MROWS*NN;             // 16 MiB
  float* av = ws + (size_t)16*1024*1024;
  float* bv = av + 16384;
  float* tv = bv + 16384;
  unsigned* bar = (unsigned*)(tv + 16384);

  dim3 blk(256);
  dim3 gEw(4096);
  dim3 gMM(2, 8, 16);
  dim3 gCT(16, 4, 16);

  adj_prep_k<<<gEw, blk, 0, stream>>>(adj, dis, rinv, adjbf);
  split_flat_k<<<dim3(32),  blk, 0, stream>>>(w_in, winh, winl, 8192);
  split_flat_k<<<dim3(128), blk, 0, stream>>>(cw1,  w1h,  w1l,  32768);
  split_flat_k<<<dim3(128), blk, 0, stream>>>(cw2,  w2h,  w2l,  32768);
  split_flat_k<<<dim3(192), blk, 0, stream>>>(m1w,  m1h,  m1l,  49152);
  split_flat_k<<<dim3(256), blk, 0, stream>>>(m2w,  m2h,  m2l,  65536);
  split_flat_k<<<dim3(2048), blk, 0, stream>>>(X, Xh, Xl, 524288);

  // input projection: hidden[:, 0:256] = X @ w_in^T + b_in
  gemm_nt_mfma_k<<<dim3(2,128), dim3(512), 0, stream>>>(Xh, Xl, IND,
                                                        winh, winl, b_in,
                                                        hidden, 768, nullptr, nullptr,
                                                        IND, 0);

  for (int l=0; l<2; l++){
    const float* h_in = hidden + l*HD;       // ld 768
    unsigned short* wl1h = w1h + (size_t)l*65536;
    unsigned short* wl1l = w1l + (size_t)l*65536;
    unsigned short* wl2h = w2h + (size_t)l*65536;
    unsigned short* wl2l = w2l + (size_t)l*65536;
    const float* b1 = cb1 + (size_t)l*HD;
    const float* b2 = cb2 + (size_t)l*HD;
    const float* a2 = ca  + (size_t)l*2*HD + HD;

    // C0 = leaky(A_hat h)
    bconv_t_k<<<gCT, blk, 0, stream>>>(h_in, 768, dis, bt);
    gemm_nn_mfma_k<<<gMM, dim3(512), 0, stream>>>(adjbf, bt, h_in, 768, dis, s2, nullptr, nullptr, 2);
    // t1 = P h ; S0 = |h - t1| (fused)
    bconv_t_k<<<gCT, blk, 0, stream>>>(h_in, 768, nullptr, bt);
    gemm_nn_mfma_k<<<gMM, dim3(512), 0, stream>>>(adjbf, bt, h_in, 768, rinv, s1, s3, nullptr, 1);
    // t2 = P t1 ; S1 = |t1 - t2| (fused)
    bconv_t_k<<<gCT, blk, 0, stream>>>(s1, HD, nullptr, bt);
    gemm_nn_mfma_k<<<gMM, dim3(512), 0, stream>>>(adjbf, bt, s1, HD, rinv, s4, s5, nullptr, 1);
    // t3 = P t2
    bconv_t_k<<<gCT, blk, 0, stream>>>(s4, HD, nullptr, bt);
    gemm_nn_mfma_k<<<gMM, dim3(512), 0, stream>>>(adjbf, bt, s4, HD, rinv, s1, nullptr, nullptr, 1);
    // t4 = P t3 ; S2 = |t2 - t4| (fused, t4 discarded)
    bconv_t_k<<<gCT, blk, 0, stream>>>(s1, HD, nullptr, bt);
    gemm_nn_mfma_k<<<gMM, dim3(512), 0, stream>>>(adjbf, bt, s1, HD, rinv, nullptr, s1, s4, 1);
    // attention combine -> split bf16 (slot3: t2 dead)
    attn_k<<<gEw, blk, 0, stream>>>(s2, s3, s5, s1, a2, s4h, s4l);
    // two linears; linear1 chains split output into linear2
    gemm_nt_mfma_k<<<dim3(2,128), dim3(512), 0, stream>>>(s4h, s4l, HD,
                                                          wl1h, wl1l, b1,
                                                          nullptr, HD, l1h, l1l,
                                                          HD, 1);
    gemm_nt_mfma_k<<<dim3(2,128), dim3(512), 0, stream>>>(l1h, l1l, HD,
                                                          wl2h, wl2l, b2,
                                                          hidden + (l+1)*HD, 768,
                                                          nullptr, nullptr, HD, 1);
  }

  // MLP head: split hidden once, then two pre-split GEMMs
  split_flat_k<<<dim3(12288), blk, 0, stream>>>(hidden, Hh, Hl, 3145728);
  gemm_nt_mfma_k<<<dim3(2,128), dim3(512), 0, stream>>>(Hh, Hl, 768,
                                                        m1h, m1l, m1b,
                                                        nullptr, HD, m1sh, m1sl,
                                                        768, 1);
  gemm_nt_mfma_k<<<dim3(8,128), dim3(512), 0, stream>>>(m1sh, m1sl, HD,
                                                        m2h, m2l, m2b,
                                                        Z0, OUTD, nullptr, nullptr,
                                                        HD, 2);

  // ---- linear-domain Sinkhorn (8-bit E, persistent) ----
  rowcolmax_k<<<dim3(256), blk, 0, stream>>>(Z0, alpha, pmaxb);
  colred_k<<<dim3(4,16), blk, 0, stream>>>(pmaxb, beta);
  build_e_k<<<dim3(16,16,16), blk, 0, stream>>>(Z0, alpha, beta, E, Et);
  hipMemsetAsync(bar, 0, 2*sizeof(unsigned), stream);
  sinkhorn_pers_k<<<dim3(NBLK), blk, 0, stream>>>(E, Et, av, bv, tv, bar, Pout);
}

// Round 6
// 1109.991 us; speedup vs baseline: 1.5975x; 1.5975x over previous
//
#include <hip/hip_runtime.h>
#include <cstdint>
#include <cstddef>

// Problem constants
#define BB 16
#define NN 1024
#define HD 256
#define IND 128
#define OUTD 1024
#define MROWS (BB*NN)          // 16384

#define LEAKY(x) ((x) >= 0.0f ? (x) : 0.01f*(x))

typedef short short8 __attribute__((ext_vector_type(8)));
typedef float f32x4 __attribute__((ext_vector_type(4)));

// 16B async global->LDS DMA. LDS dest linear; swizzle on global source + read.
#define GLL16(gsrc, ldst) __builtin_amdgcn_global_load_lds( \
    (const __attribute__((address_space(1))) unsigned int*)(gsrc), \
    (__attribute__((address_space(3))) unsigned int*)(ldst), 16, 0, 0)

// compiler-level memory fence — stops LDS ops crossing raw s_barrier
#define CFENCE() asm volatile("" ::: "memory")

// ---------------- wave helpers ----------------
__device__ inline float wave_sum(float v){
  #pragma unroll
  for (int off=32; off; off>>=1) v += __shfl_xor(v, off, 64);
  return v;
}
__device__ inline float wave_max(float v){
  #pragma unroll
  for (int off=32; off; off>>=1) v = fmaxf(v, __shfl_xor(v, off, 64));
  return v;
}

// fp32 -> bf16 round-to-nearest-even; bf16 -> fp32
__device__ inline unsigned short f2bf(float x){
  unsigned u = __float_as_uint(x);
  unsigned r = (u + 0x7fffu + ((u >> 16) & 1u)) >> 16;
  return (unsigned short)r;
}
__device__ inline float bf2f(unsigned short h){
  return __uint_as_float((unsigned)h << 16);
}

// ---- custom 8-bit float for E in (0,1]: k=(E<<3)|M, E=e-96 (e=f32 biased exp)
// value = (1+M/8)*2^(E-31); k=248 -> 1.0; floor 2^-30 (below -> 0). rel err <=6%.
__device__ inline unsigned enc_e(float x){
  unsigned u = __float_as_uint(x);
  u += 0x7FFFFu + ((u>>20)&1u);          // RTNE at 3 mantissa bits
  unsigned e = u>>23;
  if (e < 97u) return 0u;
  return ((e-96u)<<3) | ((u>>20)&7u);
}
__device__ inline float dec_e(unsigned k){
  float nrm = __uint_as_float((k + 768u) << 20);
  return k ? nrm : 0.0f;
}

// ---------------- JAX threefry2x32 gumbel noise (partitionable) ----------------
__device__ inline float gumbel_noise(unsigned m){
  const unsigned k0 = 0u, k1 = 42u;
  const unsigned ks2 = k0 ^ k1 ^ 0x1BD11BDAu;
  unsigned x0 = 0u, x1 = m;
  x0 += k0; x1 += k1;
  #define TF_ROUND(r) { x0 += x1; x1 = (x1 << (r)) | (x1 >> (32-(r))); x1 ^= x0; }
  TF_ROUND(13) TF_ROUND(15) TF_ROUND(26) TF_ROUND(6)
  x0 += k1;  x1 += ks2 + 1u;
  TF_ROUND(17) TF_ROUND(29) TF_ROUND(16) TF_ROUND(24)
  x0 += ks2; x1 += k0 + 2u;
  TF_ROUND(13) TF_ROUND(15) TF_ROUND(26) TF_ROUND(6)
  x0 += k0;  x1 += k1 + 3u;
  TF_ROUND(17) TF_ROUND(29) TF_ROUND(16) TF_ROUND(24)
  x0 += k1;  x1 += ks2 + 4u;
  TF_ROUND(13) TF_ROUND(15) TF_ROUND(26) TF_ROUND(6)
  x0 += ks2; x1 += k0 + 5u;
  #undef TF_ROUND
  unsigned bits = x0 ^ x1;
  float u = __uint_as_float((bits >> 9) | 0x3f800000u) - 1.0f;   // [0,1)
  float t = -__logf(u + 1e-20f);
  return -__logf(t + 1e-20f) * 0.05f;   // NOISE_SCALE
}

// ---------------- fused adj row stats + bf16 convert ----------------
__global__ __launch_bounds__(256) void adj_prep_k(const float* __restrict__ adj,
                                                  float* __restrict__ dis,
                                                  float* __restrict__ rinv,
                                                  unsigned short* __restrict__ abf){
  int tid = threadIdx.x, wid = tid >> 6, lane = tid & 63;
  int row = blockIdx.x*4 + wid;
  const float4* rp = (const float4*)(adj + (size_t)row*NN);
  ushort4* op = (ushort4*)(abf + (size_t)row*NN);
  float s = 0.f;
  #pragma unroll
  for (int p=0;p<4;p++){
    float4 v = rp[lane + p*64];
    s += v.x+v.y+v.z+v.w;
    ushort4 o;
    o.x = f2bf(v.x); o.y = f2bf(v.y); o.z = f2bf(v.z); o.w = f2bf(v.w);
    op[lane + p*64] = o;
  }
  s = wave_sum(s);
  if (lane==0){
    dis[row]  = 1.0f/sqrtf(s + 1.0f);
    rinv[row] = 1.0f/s;
  }
}

// ---------------- flat hi/lo split ----------------
__global__ __launch_bounds__(256) void split_flat_k(const float* __restrict__ src,
                                                    unsigned short* __restrict__ h,
                                                    unsigned short* __restrict__ l,
                                                    int n4){
  int gid = blockIdx.x*256 + threadIdx.x;
  if (gid >= n4) return;
  float4 v = ((const float4*)src)[gid];
  ushort4 hh, ll;
  hh.x = f2bf(v.x); ll.x = f2bf(v.x - bf2f(hh.x));
  hh.y = f2bf(v.y); ll.y = f2bf(v.y - bf2f(hh.y));
  hh.z = f2bf(v.z); ll.z = f2bf(v.z - bf2f(hh.z));
  hh.w = f2bf(v.w); ll.w = f2bf(v.w - bf2f(hh.w));
  ((ushort4*)h)[gid] = hh;
  ((ushort4*)l)[gid] = ll;
}

// fp32 [16][1024 i][ld] (cols 0..255) -> bf16 transposed [16][256 c][1024 i]
__global__ __launch_bounds__(256) void bconv_t_k(const float* __restrict__ in, int ld,
                                                 const float* __restrict__ scale,
                                                 unsigned short* __restrict__ outT){
  __shared__ float tile[64][68];
  int b  = blockIdx.z;
  int i0 = blockIdx.x*64;
  int c0 = blockIdx.y*64;
  const float* inb = in + (size_t)b*NN*ld;
  unsigned short* ob = outT + (size_t)b*HD*NN;
  int tid = threadIdx.x;
  #pragma unroll
  for (int it=0; it<4; it++){
    int f = tid + it*256;
    int r = f >> 4, c4 = (f & 15)*4;
    float4 v = *(const float4*)(inb + (size_t)(i0+r)*ld + c0 + c4);
    float s = scale ? scale[b*NN + i0 + r] : 1.0f;
    tile[r][c4+0]=v.x*s; tile[r][c4+1]=v.y*s; tile[r][c4+2]=v.z*s; tile[r][c4+3]=v.w*s;
  }
  __syncthreads();
  #pragma unroll
  for (int it=0; it<4; it++){
    int f = tid + it*256;
    int cl = f >> 4, r4 = (f & 15)*4;
    ushort4 o;
    o.x = f2bf(tile[r4+0][cl]);
    o.y = f2bf(tile[r4+1][cl]);
    o.z = f2bf(tile[r4+2][cl]);
    o.w = f2bf(tile[r4+3][cl]);
    *(ushort4*)(ob + (size_t)(c0+cl)*NN + i0 + r4) = o;
  }
}

// dual-output transpose: reads h once, writes dis-scaled AND plain bf16 transposes
__global__ __launch_bounds__(256) void bconv2_t_k(const float* __restrict__ in, int ld,
                                                  const float* __restrict__ scale,
                                                  unsigned short* __restrict__ outS,
                                                  unsigned short* __restrict__ outP){
  __shared__ float tile[64][68];
  __shared__ float srow[64];
  int b  = blockIdx.z;
  int i0 = blockIdx.x*64;
  int c0 = blockIdx.y*64;
  const float* inb = in + (size_t)b*NN*ld;
  unsigned short* obS = outS + (size_t)b*HD*NN;
  unsigned short* obP = outP + (size_t)b*HD*NN;
  int tid = threadIdx.x;
  if (tid < 64) srow[tid] = scale[b*NN + i0 + tid];
  #pragma unroll
  for (int it=0; it<4; it++){
    int f = tid + it*256;
    int r = f >> 4, c4 = (f & 15)*4;
    float4 v = *(const float4*)(inb + (size_t)(i0+r)*ld + c0 + c4);
    tile[r][c4+0]=v.x; tile[r][c4+1]=v.y; tile[r][c4+2]=v.z; tile[r][c4+3]=v.w;
  }
  __syncthreads();
  #pragma unroll
  for (int it=0; it<4; it++){
    int f = tid + it*256;
    int cl = f >> 4, r4 = (f & 15)*4;
    float t0 = tile[r4+0][cl], t1 = tile[r4+1][cl];
    float t2 = tile[r4+2][cl], t3 = tile[r4+3][cl];
    ushort4 p, s;
    p.x = f2bf(t0); p.y = f2bf(t1); p.z = f2bf(t2); p.w = f2bf(t3);
    s.x = f2bf(t0*srow[r4+0]); s.y = f2bf(t1*srow[r4+1]);
    s.z = f2bf(t2*srow[r4+2]); s.w = f2bf(t3*srow[r4+3]);
    size_t off = (size_t)(c0+cl)*NN + i0 + r4;
    *(ushort4*)(obP + off) = p;
    *(ushort4*)(obS + off) = s;
  }
}

// ---------------- MFMA batched GEMM: acc = adj[b] @ B[b] ----------------
// ring-4, stage-ahead-2, counted vmcnt(4), ONE barrier per K-step, XCD swizzle.
// mode 1: o = 0.5*(Bsrc[i][n] + sc_i*acc)
// mode 2: o = leaky(sc_i*(acc + sc_i*Bsrc[i][n]))
__global__ __launch_bounds__(512) void gemm_nn_mfma_k(const unsigned short* __restrict__ Abf,
                                                      const unsigned short* __restrict__ Btb,
                                                      const float* __restrict__ Bsrc, int ldb,
                                                      const float* __restrict__ rowscale,
                                                      float* __restrict__ out,
                                                      float* __restrict__ out2,
                                                      const float* __restrict__ sub,
                                                      int mode){
  __shared__ unsigned short Als[4][128][32];   // 32 KB
  __shared__ unsigned short Bls[4][128][32];   // 32 KB
  // XCD swizzle: nwg=256; consecutive s round-robin XCDs -> chunk per XCD
  int s = blockIdx.x + (blockIdx.y<<1) + (blockIdx.z<<4);
  int idx = (s&7)*32 + (s>>3);
  int b  = idx >> 4;
  int i0 = ((idx>>1)&7)*128;
  int n0 = (idx&1)*128;
  const unsigned short* Ab = Abf + (size_t)b*NN*NN + (size_t)i0*NN;
  const unsigned short* Bb = Btb + (size_t)b*HD*NN + (size_t)n0*NN;
  int tid = threadIdx.x;
  int wave = tid >> 6, lane = tid & 63;
  int quad = lane >> 4, l16 = lane & 15;
  int wr = (wave >> 2)*64;
  int wc = (wave & 3)*32;

  int r  = tid >> 2;
  int cg = (((tid & 3) ^ ((r >> 1) & 3)) << 3);   // swizzled source col
  int wbase = (tid >> 6) << 9;                    // wave's 1KB chunk in a tile
  const unsigned short* gA = Ab + (size_t)r*NN + cg;
  const unsigned short* gB = Bb + (size_t)r*NN + cg;

  auto STAGE = [&](int t){
    int buf = t & 3;
    GLL16(gA + (t<<5), &Als[buf][0][0] + wbase);
    GLL16(gB + (t<<5), &Bls[buf][0][0] + wbase);
  };

  const int NT = NN/32;   // 32
  STAGE(0); STAGE(1);

  f32x4 acc[4][2] = {};

  for (int t = 0; t < NT; ++t){
    if (t+2 < NT){
      STAGE(t+2);
      asm volatile("s_waitcnt vmcnt(4)" ::: "memory");
    } else if (t+1 < NT){
      asm volatile("s_waitcnt vmcnt(2)" ::: "memory");
    } else {
      asm volatile("s_waitcnt vmcnt(0)" ::: "memory");
    }
    __builtin_amdgcn_s_barrier();
    CFENCE();
    int buf = t & 3;
    short8 af[4];
    #pragma unroll
    for (int rt=0; rt<4; rt++){
      int R = wr + rt*16 + l16;
      af[rt] = *(const short8*)&Als[buf][R][(quad ^ ((R >> 1) & 3)) << 3];
    }
    __builtin_amdgcn_s_setprio(1);
    #pragma unroll
    for (int ct=0; ct<2; ct++){
      int Rb = wc + ct*16 + l16;
      short8 bfr = *(const short8*)&Bls[buf][Rb][(quad ^ ((Rb >> 1) & 3)) << 3];
      #pragma unroll
      for (int rt=0; rt<4; rt++)
        acc[rt][ct] = __builtin_amdgcn_mfma_f32_16x16x32_bf16(af[rt], bfr, acc[rt][ct], 0, 0, 0);
    }
    __builtin_amdgcn_s_setprio(0);
  }

  #pragma unroll
  for (int rt=0; rt<4; rt++){
    #pragma unroll
    for (int p=0; p<4; p++){
      int gr = i0 + wr + rt*16 + quad*4 + p;
      int gm = b*NN + gr;
      float sc = rowscale[gm];
      #pragma unroll
      for (int ct=0; ct<2; ct++){
        int gc = n0 + wc + ct*16 + l16;
        float a = acc[rt][ct][p];
        float src = Bsrc[(size_t)gm*ldb + gc];
        float o = (mode == 1) ? 0.5f*(src + sc*a) : LEAKY(sc*(a + sc*src));
        if (out) out[(size_t)gm*HD + gc] = o;
        if (out2){
          float sv = sub ? sub[(size_t)gm*HD + gc] : src;
          out2[(size_t)gm*HD + gc] = fabsf(sv - o);
        }
      }
    }
  }
}

// ---------------- split-bf16 MFMA linear: out = act(A @ W^T + bias) ----------------
// Interleaved 4-tile K-chunks (each tile read ONCE), ring-2 slots, stage-ahead-1,
// counted vmcnt(4), 2 barriers/step, XCD swizzle. 64 KB LDS -> 2 blocks/CU.
// act 0: none, 1: leaky, 2: sinkhorn init (Z0 = (40*tanh(x)+gumbel)/0.1)
__global__ __launch_bounds__(512) void gemm_nt_mfma_k(const unsigned short* __restrict__ Ah_,
                                                      const unsigned short* __restrict__ Al_,
                                                      int lda,
                                                      const unsigned short* __restrict__ Wh_,
                                                      const unsigned short* __restrict__ Wl_,
                                                      const float* __restrict__ bias,
                                                      float* __restrict__ out, int ldo,
                                                      unsigned short* __restrict__ outh,
                                                      unsigned short* __restrict__ outl,
                                                      int K, int act){
  __shared__ unsigned short AhL[2][128][32], AlL[2][128][32];   // 32 KB
  __shared__ unsigned short WhL[2][128][32], WlL[2][128][32];   // 32 KB
  int gx = gridDim.x;
  int sh = (gx == 2) ? 1 : 3;                 // log2(gx); gx in {2,8}
  int s = blockIdx.x + blockIdx.y*gx;
  int nwg = gx*gridDim.y;
  int idx = (s&7)*(nwg>>3) + (s>>3);
  int o0 = (idx & (gx-1))*128;
  int m0 = (idx >> sh)*128;
  int tid = threadIdx.x;
  int wave = tid >> 6, lane = tid & 63;
  int quad = lane >> 4, l16 = lane & 15;
  int wr = (wave >> 2)*64;
  int wc = (wave & 3)*32;

  int r  = tid >> 2;
  int cg = (((tid & 3) ^ ((r >> 1) & 3)) << 3);
  int wbase = (tid >> 6) << 9;
  const unsigned short* gAh = Ah_ + (size_t)(m0 + r)*lda + cg;
  const unsigned short* gAl = Al_ + (size_t)(m0 + r)*lda + cg;
  const unsigned short* gWh = Wh_ + (size_t)(o0 + r)*K + cg;
  const unsigned short* gWl = Wl_ + (size_t)(o0 + r)*K + cg;

  int NC = K >> 5;

  auto STAGE = [&](int c){
    int buf = c & 1; int kc = c << 5;
    GLL16(gAh + kc, &AhL[buf][0][0] + wbase);
    GLL16(gAl + kc, &AlL[buf][0][0] + wbase);
    GLL16(gWh + kc, &WhL[buf][0][0] + wbase);
    GLL16(gWl + kc, &WlL[buf][0][0] + wbase);
  };

  STAGE(0);

  f32x4 acc[4][2] = {};

  for (int c = 0; c < NC; ++c){
    if (c+1 < NC){
      STAGE(c+1);
      asm volatile("s_waitcnt vmcnt(4)" ::: "memory");
    } else {
      asm volatile("s_waitcnt vmcnt(0)" ::: "memory");
    }
    __builtin_amdgcn_s_barrier();
    CFENCE();
    int buf = c & 1;
    short8 ah[4], al[4];
    #pragma unroll
    for (int rt=0; rt<4; rt++){
      int R = wr + rt*16 + l16;
      int sc = (quad ^ ((R >> 1) & 3)) << 3;
      ah[rt] = *(const short8*)&AhL[buf][R][sc];
      al[rt] = *(const short8*)&AlL[buf][R][sc];
    }
    __builtin_amdgcn_s_setprio(1);
    #pragma unroll
    for (int ct=0; ct<2; ct++){
      int Rb = wc + ct*16 + l16;
      int sc = (quad ^ ((Rb >> 1) & 3)) << 3;
      short8 wh = *(const short8*)&WhL[buf][Rb][sc];
      short8 wl = *(const short8*)&WlL[buf][Rb][sc];
      #pragma unroll
      for (int rt=0; rt<4; rt++){
        acc[rt][ct] = __builtin_amdgcn_mfma_f32_16x16x32_bf16(ah[rt], wh, acc[rt][ct], 0, 0, 0);
        acc[rt][ct] = __builtin_amdgcn_mfma_f32_16x16x32_bf16(al[rt], wh, acc[rt][ct], 0, 0, 0);
        acc[rt][ct] = __builtin_amdgcn_mfma_f32_16x16x32_bf16(ah[rt], wl, acc[rt][ct], 0, 0, 0);
      }
    }
    __builtin_amdgcn_s_setprio(0);
    CFENCE();
    __builtin_amdgcn_s_barrier();
    CFENCE();
  }

  #pragma unroll
  for (int rt=0; rt<4; rt++){
    #pragma unroll
    for (int p=0; p<4; p++){
      int gm = m0 + wr + rt*16 + quad*4 + p;
      #pragma unroll
      for (int ct=0; ct<2; ct++){
        int gc = o0 + wc + ct*16 + l16;
        float v = acc[rt][ct][p] + bias[gc];
        if (act == 1){
          v = LEAKY(v);
        } else if (act == 2){
          float vcl = fminf(fmaxf(v, -15.f), 15.f);
          float e = __expf(2.f*vcl);
          float lg = 40.0f * (e - 1.f) / (e + 1.f);
          unsigned flat = (unsigned)gm*1024u + (unsigned)gc;
          v = (lg + gumbel_noise(flat)) / 0.1f;
        }
        if (out) out[(size_t)gm*ldo + gc] = v;
        if (outh){
          unsigned short hh = f2bf(v);
          outh[(size_t)gm*ldo + gc] = hh;
          outl[(size_t)gm*ldo + gc] = f2bf(v - bf2f(hh));
        }
      }
    }
  }
}

// ---------------- channel attention + combine (writes split bf16 hi/lo) ----------------
__global__ __launch_bounds__(256) void attn_k(const float* __restrict__ c0,
                                              const float* __restrict__ s0,
                                              const float* __restrict__ s1,
                                              const float* __restrict__ s2,
                                              const float* __restrict__ a2,
                                              unsigned short* __restrict__ outh,
                                              unsigned short* __restrict__ outl){
  int tid = threadIdx.x, wid = tid >> 6, lane = tid & 63;
  int row = blockIdx.x*4 + wid;
  size_t base = (size_t)row*HD + lane*4;
  float4 av = *(const float4*)(a2 + lane*4);
  float4 v[4];
  v[0] = *(const float4*)(c0 + base);
  v[1] = *(const float4*)(s0 + base);
  v[2] = *(const float4*)(s1 + base);
  v[3] = *(const float4*)(s2 + base);
  float e[4];
  #pragma unroll
  for (int c=0;c<4;c++){
    float p = fmaxf(v[c].x,0.f)*av.x + fmaxf(v[c].y,0.f)*av.y
            + fmaxf(v[c].z,0.f)*av.z + fmaxf(v[c].w,0.f)*av.w;
    e[c] = wave_sum(p);
  }
  float m = fmaxf(fmaxf(e[0],e[1]), fmaxf(e[2],e[3]));
  float w0 = expf(e[0]-m), w1 = expf(e[1]-m), w2 = expf(e[2]-m), w3 = expf(e[3]-m);
  float inv = 0.25f / (w0+w1+w2+w3);
  float4 o;
  o.x = (w0*v[0].x + w1*v[1].x + w2*v[2].x + w3*v[3].x)*inv;
  o.y = (w0*v[0].y + w1*v[1].y + w2*v[2].y + w3*v[3].y)*inv;
  o.z = (w0*v[0].z + w1*v[1].z + w2*v[2].z + w3*v[3].z)*inv;
  o.w = (w0*v[0].w + w1*v[1].w + w2*v[2].w + w3*v[3].w)*inv;
  ushort4 oh, ol;
  oh.x = f2bf(o.x); ol.x = f2bf(o.x - bf2f(oh.x));
  oh.y = f2bf(o.y); ol.y = f2bf(o.y - bf2f(oh.y));
  oh.z = f2bf(o.z); ol.z = f2bf(o.z - bf2f(oh.z));
  oh.w = f2bf(o.w); ol.w = f2bf(o.w - bf2f(oh.w));
  *(ushort4*)(outh + base) = oh;
  *(ushort4*)(outl + base) = ol;
}

// ================= linear-domain Sinkhorn (8-bit E) =================
// fused rowmax + partial colmax: one HBM pass over Z0
__global__ __launch_bounds__(256) void rowcolmax_k(const float* __restrict__ Z,
                                                   float* __restrict__ alpha,
                                                   float* __restrict__ pmax){
  __shared__ float al[64];
  int tid = threadIdx.x, wid = tid >> 6, lane = tid & 63;
  int blk = blockIdx.x;             // 256 blocks, 64-row stripes
  int r0 = blk << 6;
  #pragma unroll 1
  for (int rr=0; rr<16; ++rr){
    int lr = (wid<<4) + rr;
    const float4* rp = (const float4*)(Z + ((size_t)(r0+lr)<<10));
    float m = -3.4e38f;
    #pragma unroll
    for (int p4=0;p4<4;p4++){
      float4 v = rp[lane + p4*64];
      m = fmaxf(m, fmaxf(fmaxf(v.x,v.y), fmaxf(v.z,v.w)));
    }
    m = wave_max(m);
    if (lane==0){ al[lr] = m; alpha[r0+lr] = m; }
  }
  __syncthreads();
  int j = tid*4;
  float4 mm = make_float4(-3.4e38f,-3.4e38f,-3.4e38f,-3.4e38f);
  #pragma unroll 4
  for (int rr=0; rr<64; ++rr){
    float4 v = *(const float4*)(Z + ((size_t)(r0+rr)<<10) + j);
    float a = al[rr];
    mm.x = fmaxf(mm.x, v.x-a); mm.y = fmaxf(mm.y, v.y-a);
    mm.z = fmaxf(mm.z, v.z-a); mm.w = fmaxf(mm.w, v.w-a);
  }
  *(float4*)(pmax + ((size_t)blk<<10) + j) = mm;
}

__global__ __launch_bounds__(256) void colred_k(const float* __restrict__ pmax,
                                                float* __restrict__ beta){
  int b = blockIdx.y;
  int j = blockIdx.x*256 + threadIdx.x;
  float m = -3.4e38f;
  #pragma unroll
  for (int rc=0; rc<16; rc++)
    m = fmaxf(m, pmax[((size_t)(b*16+rc)<<10) + j]);
  beta[b*NN + j] = m;
}

// build E (8-bit row-major) and E^T (8-bit)
__global__ __launch_bounds__(256) void build_e_k(const float* __restrict__ Z,
                                                 const float* __restrict__ alpha,
                                                 const float* __restrict__ beta,
                                                 unsigned char* __restrict__ E,
                                                 unsigned char* __restrict__ Et){
  __shared__ float tile[64][65];
  int b = blockIdx.z;
  int i0 = blockIdx.y*64, j0 = blockIdx.x*64;
  const float* Zb = Z + (size_t)b*NN*NN;
  const float* ab = alpha + b*NN;
  const float* bb = beta  + b*NN;
  unsigned char* Eb  = E  + (size_t)b*NN*NN;
  unsigned char* Etb = Et + (size_t)b*NN*NN;
  int tid = threadIdx.x;
  #pragma unroll
  for (int it=0; it<4; it++){
    int f = tid + it*256;
    int r = f >> 4, c4 = (f & 15)*4;
    float4 v = *(const float4*)(Zb + (size_t)(i0+r)*NN + j0 + c4);
    float a = ab[i0+r];
    float e0 = __expf(v.x - a - bb[j0+c4+0]);
    float e1 = __expf(v.y - a - bb[j0+c4+1]);
    float e2 = __expf(v.z - a - bb[j0+c4+2]);
    float e3 = __expf(v.w - a - bb[j0+c4+3]);
    tile[r][c4+0]=e0; tile[r][c4+1]=e1; tile[r][c4+2]=e2; tile[r][c4+3]=e3;
    uchar4 o;
    o.x=(unsigned char)enc_e(e0); o.y=(unsigned char)enc_e(e1);
    o.z=(unsigned char)enc_e(e2); o.w=(unsigned char)enc_e(e3);
    *(uchar4*)(Eb + (size_t)(i0+r)*NN + j0 + c4) = o;
  }
  __syncthreads();
  #pragma unroll
  for (int it=0; it<4; it++){
    int f = tid + it*256;
    int r = f >> 4, c4 = (f & 15)*4;
    uchar4 o;
    o.x = (unsigned char)enc_e(tile[c4+0][r]);
    o.y = (unsigned char)enc_e(tile[c4+1][r]);
    o.z = (unsigned char)enc_e(tile[c4+2][r]);
    o.w = (unsigned char)enc_e(tile[c4+3][r]);
    *(uchar4*)(Etb + (size_t)(j0+r)*NN + i0 + c4) = o;
  }
}

// w[row] = (recip ? 1/ : ) sum_j M[row][j] * v[b][j]; v==null -> v=1
__global__ __launch_bounds__(256) void mv_k(const unsigned char* __restrict__ M,
                                            const float* __restrict__ v,
                                            float* __restrict__ w, int recip){
  int tid = threadIdx.x, wid = tid >> 6, lane = tid & 63;
  int row = blockIdx.x*4 + wid;
  int b = row >> 10;
  uint4 mw = *((const uint4*)(M + (size_t)row*NN) + lane);
  float s = 0.f;
  if (v){
    const float* vb = v + b*NN + lane*16;
    float4 v0 = *(const float4*)(vb);
    float4 v1 = *(const float4*)(vb+4);
    float4 v2 = *(const float4*)(vb+8);
    float4 v3 = *(const float4*)(vb+12);
    s += dec_e(mw.x&255u)*v0.x + dec_e((mw.x>>8)&255u)*v0.y
       + dec_e((mw.x>>16)&255u)*v0.z + dec_e(mw.x>>24)*v0.w;
    s += dec_e(mw.y&255u)*v1.x + dec_e((mw.y>>8)&255u)*v1.y
       + dec_e((mw.y>>16)&255u)*v1.z + dec_e(mw.y>>24)*v1.w;
    s += dec_e(mw.z&255u)*v2.x + dec_e((mw.z>>8)&255u)*v2.y
       + dec_e((mw.z>>16)&255u)*v2.z + dec_e(mw.z>>24)*v2.w;
    s += dec_e(mw.w&255u)*v3.x + dec_e((mw.w>>8)&255u)*v3.y
       + dec_e((mw.w>>16)&255u)*v3.z + dec_e(mw.w>>24)*v3.w;
  } else {
    s += dec_e(mw.x&255u) + dec_e((mw.x>>8)&255u) + dec_e((mw.x>>16)&255u) + dec_e(mw.x>>24);
    s += dec_e(mw.y&255u) + dec_e((mw.y>>8)&255u) + dec_e((mw.y>>16)&255u) + dec_e(mw.y>>24);
    s += dec_e(mw.z&255u) + dec_e((mw.z>>8)&255u) + dec_e((mw.z>>16)&255u) + dec_e(mw.z>>24);
    s += dec_e(mw.w&255u) + dec_e((mw.w>>8)&255u) + dec_e((mw.w>>16)&255u) + dec_e(mw.w>>24);
  }
  s = wave_sum(s);
  if (lane==0) w[row] = recip ? 1.0f/s : s;
}

// P_ij = E_ij * a'_i / t'_j
__global__ __launch_bounds__(256) void writep_lin_k(const unsigned char* __restrict__ E,
                                                    const float* __restrict__ ap,
                                                    const float* __restrict__ tp,
                                                    float* __restrict__ P){
  int gid = blockIdx.x*256 + threadIdx.x;
  int row = gid >> 8;
  int j = (gid & 255)*4;
  int b = row >> 10;
  uchar4 e = ((const uchar4*)E)[gid];
  float a = ap[row];
  float4 t = *(const float4*)(tp + (size_t)b*NN + j);
  float4 o;
  o.x = dec_e(e.x)*a/t.x;
  o.y = dec_e(e.y)*a/t.y;
  o.z = dec_e(e.z)*a/t.z;
  o.w = dec_e(e.w)*a/t.w;
  ((float4*)P)[gid] = o;
}

// ---------------- host orchestration ----------------
extern "C" void kernel_launch(void* const* d_in, const int* in_sizes, int n_in,
                              void* d_out, int out_size, void* d_ws, size_t ws_size,
                              hipStream_t stream){
  const float* X    = (const float*)d_in[0];
  const float* adj  = (const float*)d_in[1];
  const float* w_in = (const float*)d_in[2];
  const float* b_in = (const float*)d_in[3];
  const float* cw1  = (const float*)d_in[4];
  const float* cb1  = (const float*)d_in[5];
  const float* cw2  = (const float*)d_in[6];
  const float* cb2  = (const float*)d_in[7];
  const float* ca   = (const float*)d_in[8];
  const float* m1w  = (const float*)d_in[9];
  const float* m1b  = (const float*)d_in[10];
  const float* m2w  = (const float*)d_in[11];
  const float* m2b  = (const float*)d_in[12];

  float* outp = (float*)d_out;
  float* Pout = outp;                              // [0,16M) floats
  float* Z0   = outp + (size_t)16*1024*1024;       // bytes [64,128)MB

  const size_t SLOT = (size_t)4*1024*1024;
  float* s1 = outp + 0*SLOT;
  float* s2 = outp + 1*SLOT;
  float* s3 = outp + 2*SLOT;
  float* s4 = outp + 3*SLOT;
  float* s5 = outp + 4*SLOT;
  unsigned short* bt2   = (unsigned short*)(outp + 5*SLOT);   // [80,96) MB, layer-phase only
  unsigned short* adjbf = (unsigned short*)(outp + 6*SLOT);   // [96,128) MB

  unsigned short* Xh  = (unsigned short*)(outp + 0*SLOT);
  unsigned short* Xl  = Xh + (size_t)MROWS*IND;
  unsigned short* s4h = (unsigned short*)(outp + 3*SLOT);
  unsigned short* s4l = s4h + (size_t)MROWS*HD;
  unsigned short* l1h = (unsigned short*)(outp + 0*SLOT);
  unsigned short* l1l = l1h + (size_t)MROWS*HD;
  unsigned short* m1sh = (unsigned short*)(outp + 1*SLOT);
  unsigned short* m1sl = m1sh + (size_t)MROWS*HD;
  unsigned short* Hh = (unsigned short*)(outp + 2*SLOT);      // 24 MB
  unsigned short* Hl = Hh + (size_t)MROWS*768;                // 24 MB
  // sinkhorn stabilizers in slot 0 (dead before P write)
  float* alpha = s1;                 // 64 KB
  float* beta  = s1 + 16384;         // 64 KB
  float* pmaxb = s1 + 32768;         // 1 MB (256*1024)

  float* ws     = (float*)d_ws;
  float* hidden = ws;                                   // 12M floats (layers)
  float* dis    = ws + (size_t)12*1024*1024;
  float* rinv   = dis + 16384;
  unsigned short* bt = (unsigned short*)(rinv + 16384); // 8 MiB
  unsigned short* wsp = (unsigned short*)(ws + (size_t)15*1024*1024);
  unsigned short* winh = wsp;               unsigned short* winl = winh + 32768;
  unsigned short* w1h  = winl + 32768;      unsigned short* w1l  = w1h + 131072;
  unsigned short* w2h  = w1l + 131072;      unsigned short* w2l  = w2h + 131072;
  unsigned short* m1h  = w2l + 131072;      unsigned short* m1l  = m1h + 196608;
  unsigned short* m2h  = m1l + 196608;      unsigned short* m2l  = m2h + 262144;
  unsigned char* E  = (unsigned char*)ws;               // 16 MiB (post-layers)
  unsigned char* Et = E + (size_t)MROWS*NN;             // 16 MiB
  float* av = ws + (size_t)16*1024*1024;
  float* bv = av + 16384;
  float* tv = bv + 16384;

  dim3 blk(256);
  dim3 gEw(4096);
  dim3 gMM(2, 8, 16);
  dim3 gCT(16, 4, 16);

  adj_prep_k<<<gEw, blk, 0, stream>>>(adj, dis, rinv, adjbf);
  split_flat_k<<<dim3(32),  blk, 0, stream>>>(w_in, winh, winl, 8192);
  split_flat_k<<<dim3(128), blk, 0, stream>>>(cw1,  w1h,  w1l,  32768);
  split_flat_k<<<dim3(128), blk, 0, stream>>>(cw2,  w2h,  w2l,  32768);
  split_flat_k<<<dim3(192), blk, 0, stream>>>(m1w,  m1h,  m1l,  49152);
  split_flat_k<<<dim3(256), blk, 0, stream>>>(m2w,  m2h,  m2l,  65536);
  split_flat_k<<<dim3(2048), blk, 0, stream>>>(X, Xh, Xl, 524288);

  // input projection: hidden[:, 0:256] = X @ w_in^T + b_in
  gemm_nt_mfma_k<<<dim3(2,128), dim3(512), 0, stream>>>(Xh, Xl, IND,
                                                        winh, winl, b_in,
                                                        hidden, 768, nullptr, nullptr,
                                                        IND, 0);

  for (int l=0; l<2; l++){
    const float* h_in = hidden + l*HD;       // ld 768
    unsigned short* wl1h = w1h + (size_t)l*65536;
    unsigned short* wl1l = w1l + (size_t)l*65536;
    unsigned short* wl2h = w2h + (size_t)l*65536;
    unsigned short* wl2l = w2l + (size_t)l*65536;
    const float* b1 = cb1 + (size_t)l*HD;
    const float* b2 = cb2 + (size_t)l*HD;
    const float* a2 = ca  + (size_t)l*2*HD + HD;

    // one read of h -> scaled transpose (bt) + plain transpose (bt2)
    bconv2_t_k<<<gCT, blk, 0, stream>>>(h_in, 768, dis, bt, bt2);
    // C0 = leaky(A_hat h)
    gemm_nn_mfma_k<<<gMM, dim3(512), 0, stream>>>(adjbf, bt, h_in, 768, dis, s2, nullptr, nullptr, 2);
    // t1 = P h ; S0 = |h - t1| (fused)
    gemm_nn_mfma_k<<<gMM, dim3(512), 0, stream>>>(adjbf, bt2, h_in, 768, rinv, s1, s3, nullptr, 1);
    // t2 = P t1 ; S1 = |t1 - t2| (fused)
    bconv_t_k<<<gCT, blk, 0, stream>>>(s1, HD, nullptr, bt);
    gemm_nn_mfma_k<<<gMM, dim3(512), 0, stream>>>(adjbf, bt, s1, HD, rinv, s4, s5, nullptr, 1);
    // t3 = P t2
    bconv_t_k<<<gCT, blk, 0, stream>>>(s4, HD, nullptr, bt);
    gemm_nn_mfma_k<<<gMM, dim3(512), 0, stream>>>(adjbf, bt, s4, HD, rinv, s1, nullptr, nullptr, 1);
    // t4 = P t3 ; S2 = |t2 - t4| (fused, t4 discarded)
    bconv_t_k<<<gCT, blk, 0, stream>>>(s1, HD, nullptr, bt);
    gemm_nn_mfma_k<<<gMM, dim3(512), 0, stream>>>(adjbf, bt, s1, HD, rinv, nullptr, s1, s4, 1);
    // attention combine -> split bf16 (slot3: t2 dead)
    attn_k<<<gEw, blk, 0, stream>>>(s2, s3, s5, s1, a2, s4h, s4l);
    // two linears; linear1 chains split output into linear2
    gemm_nt_mfma_k<<<dim3(2,128), dim3(512), 0, stream>>>(s4h, s4l, HD,
                                                          wl1h, wl1l, b1,
                                                          nullptr, HD, l1h, l1l,
                                                          HD, 1);
    gemm_nt_mfma_k<<<dim3(2,128), dim3(512), 0, stream>>>(l1h, l1l, HD,
                                                          wl2h, wl2l, b2,
                                                          hidden + (l+1)*HD, 768,
                                                          nullptr, nullptr, HD, 1);
  }

  // MLP head: split hidden once, then two pre-split GEMMs
  split_flat_k<<<dim3(12288), blk, 0, stream>>>(hidden, Hh, Hl, 3145728);
  gemm_nt_mfma_k<<<dim3(2,128), dim3(512), 0, stream>>>(Hh, Hl, 768,
                                                        m1h, m1l, m1b,
                                                        nullptr, HD, m1sh, m1sl,
                                                        768, 1);
  gemm_nt_mfma_k<<<dim3(8,128), dim3(512), 0, stream>>>(m1sh, m1sl, HD,
                                                        m2h, m2l, m2b,
                                                        Z0, OUTD, nullptr, nullptr,
                                                        HD, 2);

  // ---- linear-domain Sinkhorn (8-bit E, launch-based) ----
  rowcolmax_k<<<dim3(256), blk, 0, stream>>>(Z0, alpha, pmaxb);
  colred_k<<<dim3(4,16), blk, 0, stream>>>(pmaxb, beta);
  build_e_k<<<dim3(16,16,16), blk, 0, stream>>>(Z0, alpha, beta, E, Et);

  mv_k<<<gEw, blk, 0, stream>>>(E,  nullptr, av, 1);   // iter 1: b=1
  mv_k<<<gEw, blk, 0, stream>>>(Et, av,      bv, 1);
  for (int t=1; t<20; t++){
    mv_k<<<gEw, blk, 0, stream>>>(E,  bv, av, 1);
    mv_k<<<gEw, blk, 0, stream>>>(Et, av, bv, 1);
  }
  mv_k<<<gEw, blk, 0, stream>>>(E,  bv, av, 1);        // a' (row normalize)
  mv_k<<<gEw, blk, 0, stream>>>(Et, av, tv, 0);        // t' = col sums
  writep_lin_k<<<dim3(16384), blk, 0, stream>>>(E, av, tv, Pout);
}